// Round 5
// baseline (588.882 us; speedup 1.0000x reference)
//
#include <hip/hip_runtime.h>
#include <cstdint>
#include <cstddef>

#define N_IN  700
#define N_INP 704           // K padded to 32
#define N_HID 512
#define N_OUT 20
#define BB    256
#define TT    100
#define NK    (BB*TT)       // 25600
#define NCH   8             // split-k chunks for gf/gr

__device__ __constant__ const float TAU   = 0.6f;
__device__ __constant__ const float TAU_O = 0.6f;
__device__ __constant__ const float THR   = 0.6f;
__device__ __constant__ const float GAM   = 0.3f;

typedef float f32x4 __attribute__((ext_vector_type(4)));
typedef __bf16 bf16x8 __attribute__((ext_vector_type(8)));

__device__ __forceinline__ unsigned short f2bf_rne(float f) {
  uint32_t b = __builtin_bit_cast(uint32_t, f);
  uint32_t r = (b + 0x7FFFu + ((b >> 16) & 1u)) >> 16;
  return (unsigned short)r;
}
__device__ __forceinline__ float bf2f(unsigned short u) {
  uint32_t b = ((uint32_t)u) << 16;
  return __builtin_bit_cast(float, b);
}

// ---------------- prep: W split into hi+lo bf16, [r][i] layout padded to 704 ----------------
__global__ void k_wsplit(const float* __restrict__ W1,
                         unsigned short* __restrict__ WH,
                         unsigned short* __restrict__ WL) {
  int g = blockIdx.x*256 + threadIdx.x;
  if (g >= N_HID*88) return;
  int r = g / 88, c = g - (g/88)*88;
  int ib = c*8;
  unsigned short h[8], l[8];
  #pragma unroll
  for (int j = 0; j < 8; ++j) {
    int i = ib + j;
    float v = (i < N_IN) ? W1[r*N_IN + i] : 0.f;
    unsigned short hh = f2bf_rne(v);
    float res = v - bf2f(hh);
    h[j] = hh;
    l[j] = f2bf_rne(res);
  }
  uint4 hv = make_uint4((uint32_t)h[0] | ((uint32_t)h[1]<<16), (uint32_t)h[2] | ((uint32_t)h[3]<<16),
                        (uint32_t)h[4] | ((uint32_t)h[5]<<16), (uint32_t)h[6] | ((uint32_t)h[7]<<16));
  uint4 lv = make_uint4((uint32_t)l[0] | ((uint32_t)l[1]<<16), (uint32_t)l[2] | ((uint32_t)l[3]<<16),
                        (uint32_t)l[4] | ((uint32_t)l[5]<<16), (uint32_t)l[6] | ((uint32_t)l[7]<<16));
  *(uint4*)(WH + (size_t)r*N_INP + ib) = hv;
  *(uint4*)(WL + (size_t)r*N_INP + ib) = lv;
}

__global__ void k_prep_t2(const float* __restrict__ Wr, float* __restrict__ WRT) {
  int g = blockIdx.x*256 + threadIdx.x;
  if (g < N_HID*N_HID) {
    int j = g >> 9, r = g & 511;
    WRT[g] = Wr[r*N_HID + j];
  }
}
// NOTE: summation order of Srow/SOs is spike-determining — keep serial order exactly.
__global__ void k_prep_sums(const float* __restrict__ Wr, const float* __restrict__ Wo,
                            float* __restrict__ Srow, float* __restrict__ SOs,
                            int* __restrict__ tmax) {
  int g = blockIdx.x*256 + threadIdx.x;
  if (g < N_HID) {
    float s = 0.f;
    for (int j = 0; j < N_HID; ++j) s += Wr[g*N_HID + j];
    Srow[g] = s;
  } else if (g < N_HID + N_OUT) {
    int o = g - N_HID;
    float s = 0.f;
    for (int r = 0; r < N_HID; ++r) s += Wo[o*N_HID + r];
    SOs[o] = s;
  }
  if (g < BB) tmax[g] = 0;
}

// ---------------- phase A: INL = X @ (WH^T + WL^T), MFMA split-bf16 ----------------
__global__ __launch_bounds__(256) void k_gemm(const float* __restrict__ x,
                                              const unsigned short* __restrict__ WH,
                                              const unsigned short* __restrict__ WL,
                                              float* __restrict__ INL) {
  __shared__ __align__(16) unsigned short sA [128*32];
  __shared__ __align__(16) unsigned short sBh[128*32];
  __shared__ __align__(16) unsigned short sBl[128*32];
  const int tid = threadIdx.x, lane = tid & 63, w = tid >> 6;
  const int k0 = blockIdx.x * 128;
  const int c0 = blockIdx.y * 128;
  const int wr = w >> 1, wc = w & 1;
  const int fr = lane & 15, fk = lane >> 4;

  const int a_r  = tid >> 1;
  const int a_cb = (tid & 1) * 16;
  const int b_r  = tid >> 2;
  const int b_c  = (tid & 3) * 8;

  const float* xr = x + (size_t)(k0 + a_r) * N_IN;
  const unsigned short* gh = WH + (size_t)(c0 + b_r) * N_INP;
  const unsigned short* gl = WL + (size_t)(c0 + b_r) * N_INP;

  f32x4 acc[4][4];
  #pragma unroll
  for (int m = 0; m < 4; ++m)
    #pragma unroll
    for (int n = 0; n < 4; ++n)
      acc[m][n] = (f32x4){0.f, 0.f, 0.f, 0.f};

  for (int s = 0; s < N_INP/32; ++s) {
    const int i0 = s * 32;
    float av[16];
    const int col0 = i0 + a_cb;
    if (col0 + 16 <= N_IN) {
      float4 t0 = *(const float4*)(xr + col0);
      float4 t1 = *(const float4*)(xr + col0 + 4);
      float4 t2 = *(const float4*)(xr + col0 + 8);
      float4 t3 = *(const float4*)(xr + col0 + 12);
      av[0]=t0.x; av[1]=t0.y; av[2]=t0.z; av[3]=t0.w;
      av[4]=t1.x; av[5]=t1.y; av[6]=t1.z; av[7]=t1.w;
      av[8]=t2.x; av[9]=t2.y; av[10]=t2.z; av[11]=t2.w;
      av[12]=t3.x; av[13]=t3.y; av[14]=t3.z; av[15]=t3.w;
    } else {
      #pragma unroll
      for (int j = 0; j < 16; ++j) av[j] = (col0 + j < N_IN) ? xr[col0 + j] : 0.f;
    }
    uint32_t us[8];
    #pragma unroll
    for (int p = 0; p < 8; ++p) {
      uint32_t lo = __builtin_bit_cast(uint32_t, av[2*p])   >> 16;
      uint32_t hi = __builtin_bit_cast(uint32_t, av[2*p+1]) & 0xFFFF0000u;
      us[p] = hi | lo;
    }
    *(uint4*)&sA[a_r*32 + a_cb]     = make_uint4(us[0], us[1], us[2], us[3]);
    *(uint4*)&sA[a_r*32 + a_cb + 8] = make_uint4(us[4], us[5], us[6], us[7]);
    *(uint4*)&sBh[b_r*32 + b_c]      = *(const uint4*)(gh + i0 + b_c);
    *(uint4*)&sBh[(b_r+64)*32 + b_c] = *(const uint4*)(gh + (size_t)64*N_INP + i0 + b_c);
    *(uint4*)&sBl[b_r*32 + b_c]      = *(const uint4*)(gl + i0 + b_c);
    *(uint4*)&sBl[(b_r+64)*32 + b_c] = *(const uint4*)(gl + (size_t)64*N_INP + i0 + b_c);
    __syncthreads();

    bf16x8 a[4], bh[4], bl[4];
    #pragma unroll
    for (int m = 0; m < 4; ++m)
      a[m] = *(const bf16x8*)&sA[(wr*64 + m*16 + fr)*32 + fk*8];
    #pragma unroll
    for (int n = 0; n < 4; ++n) {
      bh[n] = *(const bf16x8*)&sBh[(wc*64 + n*16 + fr)*32 + fk*8];
      bl[n] = *(const bf16x8*)&sBl[(wc*64 + n*16 + fr)*32 + fk*8];
    }
    #pragma unroll
    for (int m = 0; m < 4; ++m)
      #pragma unroll
      for (int n = 0; n < 4; ++n) {
        acc[m][n] = __builtin_amdgcn_mfma_f32_16x16x32_bf16(a[m], bh[n], acc[m][n], 0, 0, 0);
        acc[m][n] = __builtin_amdgcn_mfma_f32_16x16x32_bf16(a[m], bl[n], acc[m][n], 0, 0, 0);
      }
    __syncthreads();
  }
  #pragma unroll
  for (int m = 0; m < 4; ++m) {
    #pragma unroll
    for (int n = 0; n < 4; ++n) {
      #pragma unroll
      for (int reg = 0; reg < 4; ++reg) {
        const int row = k0 + wr*64 + m*16 + (lane>>4)*4 + reg;
        const int col = c0 + wc*64 + n*16 + fr;
        INL[(size_t)row*N_HID + col] = acc[m][n][reg];
      }
    }
  }
}

// ---------------- phase B: sequential scan, replicated output state, 1 barrier fast path ----------------
__global__ __launch_bounds__(256) void k_scan(
    float* __restrict__ INL, const float* __restrict__ label,
    const float* __restrict__ Wo, const float* __restrict__ WRT,
    const float* __restrict__ Srow, const float* __restrict__ SOs,
    unsigned long long* __restrict__ hsbits, float* __restrict__ outs,
    float* __restrict__ pgo)
{
  const int b = blockIdx.x, tid = threadIdx.x;
  const int lane = tid & 63, w = tid >> 6;
  const int po = tid / 12, pc2 = tid - po*12;
  __shared__ float sWo[N_OUT*N_HID];              // 40 KB
  __shared__ int   list[N_HID];
  __shared__ unsigned long long masks[2][8];
  __shared__ float part[N_OUT][13];
  __shared__ float compl_s[N_OUT];

  for (int idx = tid; idx < N_OUT*N_HID; idx += 256) sWo[idx] = Wo[idx];

  float hm0 = 0.f, hm1 = 0.f;
  int   hs0 = 0,   hs1 = 0;
  float tout0 = 0.f, tout1 = 0.f;
  float om[N_OUT], err[N_OUT], SOsr[N_OUT], go0[N_OUT], go1[N_OUT];
  uint32_t omask = 0;
  #pragma unroll
  for (int o = 0; o < N_OUT; ++o) { om[o] = 0.f; go0[o] = 0.f; go1[o] = 0.f; }
  {
    float4 s0v = *(const float4*)(SOs);
    float4 s1v = *(const float4*)(SOs + 4);
    float4 s2v = *(const float4*)(SOs + 8);
    float4 s3v = *(const float4*)(SOs + 12);
    float4 s4v = *(const float4*)(SOs + 16);
    SOsr[0]=s0v.x; SOsr[1]=s0v.y; SOsr[2]=s0v.z; SOsr[3]=s0v.w;
    SOsr[4]=s1v.x; SOsr[5]=s1v.y; SOsr[6]=s1v.z; SOsr[7]=s1v.w;
    SOsr[8]=s2v.x; SOsr[9]=s2v.y; SOsr[10]=s2v.z; SOsr[11]=s2v.w;
    SOsr[12]=s3v.x; SOsr[13]=s3v.y; SOsr[14]=s3v.z; SOsr[15]=s3v.w;
    SOsr[16]=s4v.x; SOsr[17]=s4v.y; SOsr[18]=s4v.z; SOsr[19]=s4v.w;
  }
  int cnt_prev = 0, mode_prev = 0;

  const size_t base = (size_t)b*TT;
  float in0 = INL[base*N_HID + tid];
  float in1 = INL[base*N_HID + 256 + tid];
  const float srow0 = Srow[tid], srow1 = Srow[256 + tid];
  __syncthreads();                                 // sWo ready

  for (int t = 0; t < TT; ++t) {
    const size_t k  = base + t;
    const size_t kn = (t < TT-1) ? (k + 1) : k;
    // issue loads early: this step's labels + next step's IN
    float4 l4[5];
    #pragma unroll
    for (int q = 0; q < 5; ++q) l4[q] = *(const float4*)(label + k*N_OUT + 4*q);
    const float nin0 = INL[kn*N_HID + tid];
    const float nin1 = INL[kn*N_HID + 256 + tid];

    float s0 = 0.f, s1 = 0.f;
    if (cnt_prev > 0) {                            // block-uniform
      for (int it = 0; it < cnt_prev; ++it) {
        const int j = list[it];
        s0 += WRT[j*N_HID + tid];
        s1 += WRT[j*N_HID + 256 + tid];
      }
    }
    const float rec0 = mode_prev ? (srow0 - s0) : s0;
    const float rec1 = mode_prev ? (srow1 - s1) : s1;

    const float nhm0 = TAU*hm0*(hs0 ? 0.f : 1.f) + in0 + rec0;
    const float nhm1 = TAU*hm1*(hs1 ? 0.f : 1.f) + in1 + rec1;
    const int nhs0 = (nhm0 >= THR) ? 1 : 0;
    const int nhs1 = (nhm1 >= THR) ? 1 : 0;

    const unsigned long long mA = __ballot(nhs0 != 0);
    const unsigned long long mB = __ballot(nhs1 != 0);
    const int p = t & 1;
    if (lane == 0) { masks[p][w] = mA; masks[p][4 + w] = mB; }
    __syncthreads();                               // barrier A (only one in fast path)

    if (tid < 8) hsbits[k*8 + tid] = masks[p][tid];
    int pcs[8];
    #pragma unroll
    for (int q = 0; q < 8; ++q) pcs[q] = (int)__popcll(masks[p][q]);
    const int ctot = pcs[0]+pcs[1]+pcs[2]+pcs[3]+pcs[4]+pcs[5]+pcs[6]+pcs[7];
    const int mode = (ctot <= 256) ? 0 : 1;
    int pre[8];
    pre[0] = 0;
    #pragma unroll
    for (int q = 1; q < 8; ++q) pre[q] = pre[q-1] + (mode ? 64 - pcs[q-1] : pcs[q-1]);
    const int cnt = pre[7] + (mode ? 64 - pcs[7] : pcs[7]);

    float gath[N_OUT];
    if (cnt != 0) {                                // slow path (~2 steps of 100), block-uniform
      {
        const unsigned long long below = (1ULL << lane) - 1ULL;
        const unsigned long long sm0 = mode ? ~mA : mA;
        const unsigned long long sm1 = mode ? ~mB : mB;
        if (mode ? !nhs0 : nhs0) list[pre[w]     + (int)__popcll(sm0 & below)] = tid;
        if (mode ? !nhs1 : nhs1) list[pre[4 + w] + (int)__popcll(sm1 & below)] = tid + 256;
      }
      __syncthreads();
      if (tid < 240) {
        float s = 0.f;
        for (int it = pc2; it < cnt; it += 12) s += sWo[po*N_HID + list[it]];
        part[po][pc2] = s;
      }
      __syncthreads();
      if (tid < N_OUT) {
        float dsum = 0.f;
        #pragma unroll
        for (int c2 = 0; c2 < 12; ++c2) dsum += part[tid][c2];
        compl_s[tid] = dsum;
      }
      __syncthreads();
      #pragma unroll
      for (int o = 0; o < N_OUT; ++o) gath[o] = compl_s[o];
    } else {
      #pragma unroll
      for (int o = 0; o < N_OUT; ++o) gath[o] = 0.f;
    }

    // replicated output-neuron update (identical FP sequence in every thread)
    float la[N_OUT];
    #pragma unroll
    for (int q = 0; q < 5; ++q) {
      la[4*q+0] = l4[q].x; la[4*q+1] = l4[q].y; la[4*q+2] = l4[q].z; la[4*q+3] = l4[q].w;
    }
    uint32_t nosmask = 0;
    #pragma unroll
    for (int o = 0; o < N_OUT; ++o) {
      const float drive = mode ? (SOsr[o] - gath[o]) : gath[o];
      om[o] = TAU*om[o]*(((omask >> o) & 1u) ? 0.f : 1.f) + drive;
      const int nos = (om[o] >= THR) ? 1 : 0;
      nosmask |= ((uint32_t)nos) << o;
      err[o] = (nos ? 1.f : 0.f) - la[o];
    }
    omask = nosmask;
    if (tid < N_OUT) outs[k*N_OUT + tid] = (float)((nosmask >> tid) & 1u);

    float d0 = 0.f, d1 = 0.f;
    #pragma unroll
    for (int o = 0; o < N_OUT; ++o) {
      const float e = err[o];
      if (e != 0.f) {                              // block-uniform (err replicated)
        d0 += e * sWo[o*N_HID + tid];
        d1 += e * sWo[o*N_HID + 256 + tid];
      }
    }
    const float a0f = fabsf(nhm0 - THR) / THR;
    const float a1f = fabsf(nhm1 - THR) / THR;
    const float ht0 = GAM * fmaxf(0.f, 1.f - a0f);
    const float ht1 = GAM * fmaxf(0.f, 1.f - a1f);
    INL[k*N_HID + tid]       = d0 * ht0;
    INL[k*N_HID + 256 + tid] = d1 * ht1;

    tout0 = TAU_O*tout0 + (nhs0 ? 1.f : 0.f);
    tout1 = TAU_O*tout1 + (nhs1 ? 1.f : 0.f);
    #pragma unroll
    for (int o = 0; o < N_OUT; ++o) {
      const float e = err[o];
      go0[o] += e * tout0;
      go1[o] += e * tout1;
    }

    hm0 = nhm0; hm1 = nhm1; hs0 = nhs0; hs1 = nhs1;
    cnt_prev = cnt; mode_prev = mode;
    in0 = nin0; in1 = nin1;
  }
  #pragma unroll
  for (int o = 0; o < N_OUT; ++o) {
    pgo[((size_t)b*N_OUT + o)*N_HID + tid]       = go0[o];
    pgo[((size_t)b*N_OUT + o)*N_HID + 256 + tid] = go1[o];
  }
}

// ---------------- phase C: reverse filter with 1-deep prefetch ----------------
__global__ void k_mfilter(float* __restrict__ L, int* __restrict__ tmax) {
  const int g = blockIdx.x*256 + threadIdx.x;   // (b, r)
  const int b = g >> 9, r = g & 511;
  const size_t rowbase = (size_t)b*TT;
  float m = 0.f;
  int last = -1;
  float cur = L[(rowbase + TT - 1)*N_HID + r];
  for (int t = TT - 1; t >= 0; --t) {
    const float nxt = (t > 0) ? L[(rowbase + t - 1)*N_HID + r] : 0.f;
    const float v = cur + TAU*m;
    L[(rowbase + t)*N_HID + r] = v;
    m = v;
    if (v != 0.f && last < 0) last = t;
    cur = nxt;
  }
  if (last >= 0) atomicMax(tmax + b, last + 1);
}

// ---------------- phase D: go = 0.1 * sum_b pgo[b]  (160 blocks, 4-way b-split, ordered reduce) ----------------
__global__ __launch_bounds__(256) void k_go(const float* __restrict__ pgo, float* __restrict__ go) {
  __shared__ float red[4][64];
  const int l = threadIdx.x & 63;
  const int ch = threadIdx.x >> 6;
  const int col = blockIdx.x*64 + l;
  float s = 0.f;
  for (int b2 = ch*64; b2 < ch*64 + 64; ++b2)
    s += pgo[(size_t)b2*(N_OUT*N_HID) + col];
  red[ch][l] = s;
  __syncthreads();
  if (ch == 0) go[col] = 0.1f*(((red[0][l] + red[1][l]) + red[2][l]) + red[3][l]);
}

// ---------------- phase D: gf partials over b-chunks ----------------
__global__ __launch_bounds__(256) void k_gf(const float* __restrict__ M, const float* __restrict__ x,
                                            const int* __restrict__ tmax,
                                            float* __restrict__ gfp) {
  const int lane = threadIdx.x & 63, w = threadIdx.x >> 6;
  const int r  = blockIdx.x*64 + lane;
  const int i0 = blockIdx.y*64 + w*16;
  const int ch = blockIdx.z;
  const int b_lo = ch * (BB/NCH);
  __shared__ int cnt_sh[BB/NCH];
  if (threadIdx.x < BB/NCH) cnt_sh[threadIdx.x] = tmax[b_lo + threadIdx.x];
  __syncthreads();
  float acc[16];
  #pragma unroll
  for (int ii = 0; ii < 16; ++ii) acc[ii] = 0.f;
  int xi = i0 + (lane & 15); if (xi > N_IN - 1) xi = N_IN - 1;
  for (int bi = 0; bi < BB/NCH; ++bi) {
    const int ct = cnt_sh[bi];
    if (ct == 0) continue;
    const size_t kb = (size_t)(b_lo + bi)*TT;
    float mv = M[kb*N_HID + r];
    float xv = x[kb*N_IN + xi];
    for (int t = 0; t < ct; ++t) {
      float mv_n = 0.f, xv_n = 0.f;
      if (t + 1 < ct) {
        mv_n = M[(kb + t + 1)*N_HID + r];
        xv_n = x[(kb + t + 1)*N_IN + xi];
      }
      #pragma unroll
      for (int ii = 0; ii < 16; ++ii) acc[ii] += mv * __shfl(xv, ii);
      mv = mv_n; xv = xv_n;
    }
  }
  #pragma unroll
  for (int ii = 0; ii < 16; ++ii) {
    const int i = i0 + ii;
    if (i < N_IN) gfp[(size_t)ch*(N_HID*N_IN) + (size_t)r*N_IN + i] = acc[ii];
  }
}

// ---------------- phase D: gr partials over b-chunks ----------------
__global__ __launch_bounds__(256) void k_gr(const float* __restrict__ M,
                                            const unsigned long long* __restrict__ hsbits,
                                            const int* __restrict__ tmax,
                                            float* __restrict__ grp) {
  const int lane = threadIdx.x & 63, w = threadIdx.x >> 6;
  const int r  = blockIdx.x*64 + lane;
  const int h0 = blockIdx.y*64 + w*16;
  const int ch = blockIdx.z;
  const int b_lo = ch * (BB/NCH);
  __shared__ int cnt_sh[BB/NCH];
  if (threadIdx.x < BB/NCH) cnt_sh[threadIdx.x] = tmax[b_lo + threadIdx.x];
  __syncthreads();
  float acc[16];
  #pragma unroll
  for (int ii = 0; ii < 16; ++ii) acc[ii] = 0.f;
  const int hw = h0 >> 6, sh = h0 & 63;
  for (int bi = 0; bi < BB/NCH; ++bi) {
    const int ct = cnt_sh[bi];
    if (ct == 0) continue;
    const size_t kb = (size_t)(b_lo + bi)*TT;
    float mv = M[kb*N_HID + r];
    unsigned long long word = hsbits[kb*8 + hw];
    for (int t = 0; t < ct; ++t) {
      float mv_n = 0.f; unsigned long long word_n = 0ULL;
      if (t + 1 < ct) {
        mv_n = M[(kb + t + 1)*N_HID + r];
        word_n = hsbits[(kb + t + 1)*8 + hw];
      }
      #pragma unroll
      for (int ii = 0; ii < 16; ++ii)
        if ((word >> (sh + ii)) & 1ULL) acc[ii] += mv;
      mv = mv_n; word = word_n;
    }
  }
  #pragma unroll
  for (int ii = 0; ii < 16; ++ii)
    grp[(size_t)ch*(N_HID*N_HID) + (size_t)r*N_HID + h0 + ii] = acc[ii];
}

// ---------------- phase D: deterministic partial reductions ----------------
__global__ void k_gfred(const float* __restrict__ gfp, float* __restrict__ gf) {
  const int g = blockIdx.x*256 + threadIdx.x;
  if (g < N_HID*N_IN) {
    float s = 0.f;
    #pragma unroll
    for (int c = 0; c < NCH; ++c) s += gfp[(size_t)c*(N_HID*N_IN) + g];
    gf[g] = 0.1f*s;
  }
}
__global__ void k_grred(const float* __restrict__ grp, float* __restrict__ gr) {
  const int g = blockIdx.x*256 + threadIdx.x;
  if (g < N_HID*N_HID) {
    float s = 0.f;
    #pragma unroll
    for (int c = 0; c < NCH; ++c) s += grp[(size_t)c*(N_HID*N_HID) + g];
    gr[g] = 0.1f*s;
  }
}

extern "C" void kernel_launch(void* const* d_in, const int* in_sizes, int n_in,
                              void* d_out, int out_size, void* d_ws, size_t ws_size,
                              hipStream_t stream) {
  const float* x     = (const float*)d_in[0];
  const float* label = (const float*)d_in[1];
  const float* W1    = (const float*)d_in[2];
  const float* Wr    = (const float*)d_in[3];
  const float* Wo    = (const float*)d_in[4];

  float* out  = (float*)d_out;
  float* outs = out;                                    // [256][100][20]
  float* gf   = out + 512000;                           // [512][700]
  float* gr   = out + 512000 + 358400;                  // [512][512]
  float* go   = out + 512000 + 358400 + 262144;         // [20][512]

  char* ws = (char*)d_ws;
  size_t off = 0;
  auto alloc = [&](size_t bytes) -> char* {
    char* p = ws + off;
    off += (bytes + 255) & ~(size_t)255;
    return p;
  };
  float* INL = (float*)alloc((size_t)NK*N_HID*sizeof(float));                    // 52.43 MB
  unsigned long long* hsb = (unsigned long long*)alloc((size_t)NK*8*sizeof(unsigned long long)); // 1.64 MB
  int* tmax = (int*)alloc((size_t)BB*sizeof(int));
  char* uni = alloc((size_t)20971520);                                           // 20 MB union region

  // early residents of uni (dead after k_go)
  unsigned short* WH = (unsigned short*)(uni);                                   // 0.72 MB
  unsigned short* WL = (unsigned short*)(uni + 720896);                          // 0.72 MB
  float* WRT  = (float*)(uni + 2*720896);                                        // 1.05 MB
  float* Srow = (float*)(uni + 2*720896 + 1048576);
  float* SOs  = (float*)(uni + 2*720896 + 1048576 + 2048);
  float* pgo  = (float*)(uni + 2*720896 + 1048576 + 4096);                       // 10.49 MB
  // late residents of uni (written only after k_go has consumed pgo)
  float* gfp  = (float*)(uni);                                                   // 11.47 MB
  float* grp  = (float*)(uni + (size_t)NCH*N_HID*N_IN*sizeof(float));            // 8.39 MB

  k_wsplit<<<(N_HID*88 + 255)/256, 256, 0, stream>>>(W1, WH, WL);
  k_prep_t2<<<(N_HID*N_HID + 255)/256, 256, 0, stream>>>(Wr, WRT);
  k_prep_sums<<<(N_HID + N_OUT + 255)/256, 256, 0, stream>>>(Wr, Wo, Srow, SOs, tmax);
  dim3 gg(NK/128, N_HID/128);
  k_gemm<<<gg, 256, 0, stream>>>(x, WH, WL, INL);
  k_scan<<<BB, 256, 0, stream>>>(INL, label, Wo, WRT, Srow, SOs, hsb, outs, pgo);
  k_mfilter<<<(BB*N_HID)/256, 256, 0, stream>>>(INL, tmax);
  k_go<<<(N_OUT*N_HID)/64, 256, 0, stream>>>(pgo, go);
  dim3 ggf(8, 11, NCH); k_gf<<<ggf, 256, 0, stream>>>(INL, x, tmax, gfp);
  dim3 ggr(8, 8, NCH);  k_gr<<<ggr, 256, 0, stream>>>(INL, hsb, tmax, grp);
  k_gfred<<<(N_HID*N_IN + 255)/256, 256, 0, stream>>>(gfp, gf);
  k_grred<<<(N_HID*N_HID + 255)/256, 256, 0, stream>>>(grp, gr);
}

// Round 6
// 537.000 us; speedup vs baseline: 1.0966x; 1.0966x over previous
//
#include <hip/hip_runtime.h>
#include <cstdint>
#include <cstddef>

#define N_IN  700
#define N_INP 704           // K padded to 32
#define N_HID 512
#define N_OUT 20
#define BB    256
#define TT    100
#define NK    (BB*TT)       // 25600
#define NCH   8             // split-k chunks for gf/gr

__device__ __constant__ const float TAU   = 0.6f;
__device__ __constant__ const float TAU_O = 0.6f;
__device__ __constant__ const float THR   = 0.6f;
__device__ __constant__ const float GAM   = 0.3f;

typedef float f32x4 __attribute__((ext_vector_type(4)));
typedef __bf16 bf16x8 __attribute__((ext_vector_type(8)));

__device__ __forceinline__ unsigned short f2bf_rne(float f) {
  uint32_t b = __builtin_bit_cast(uint32_t, f);
  uint32_t r = (b + 0x7FFFu + ((b >> 16) & 1u)) >> 16;
  return (unsigned short)r;
}
__device__ __forceinline__ float bf2f(unsigned short u) {
  uint32_t b = ((uint32_t)u) << 16;
  return __builtin_bit_cast(float, b);
}

// ---------------- prep: W split into hi+lo bf16, [r][i] layout padded to 704 ----------------
__global__ void k_wsplit(const float* __restrict__ W1,
                         unsigned short* __restrict__ WH,
                         unsigned short* __restrict__ WL) {
  int g = blockIdx.x*256 + threadIdx.x;
  if (g >= N_HID*88) return;
  int r = g / 88, c = g - (g/88)*88;
  int ib = c*8;
  unsigned short h[8], l[8];
  #pragma unroll
  for (int j = 0; j < 8; ++j) {
    int i = ib + j;
    float v = (i < N_IN) ? W1[r*N_IN + i] : 0.f;
    unsigned short hh = f2bf_rne(v);
    float res = v - bf2f(hh);
    h[j] = hh;
    l[j] = f2bf_rne(res);
  }
  uint4 hv = make_uint4((uint32_t)h[0] | ((uint32_t)h[1]<<16), (uint32_t)h[2] | ((uint32_t)h[3]<<16),
                        (uint32_t)h[4] | ((uint32_t)h[5]<<16), (uint32_t)h[6] | ((uint32_t)h[7]<<16));
  uint4 lv = make_uint4((uint32_t)l[0] | ((uint32_t)l[1]<<16), (uint32_t)l[2] | ((uint32_t)l[3]<<16),
                        (uint32_t)l[4] | ((uint32_t)l[5]<<16), (uint32_t)l[6] | ((uint32_t)l[7]<<16));
  *(uint4*)(WH + (size_t)r*N_INP + ib) = hv;
  *(uint4*)(WL + (size_t)r*N_INP + ib) = lv;
}

__global__ void k_prep_t2(const float* __restrict__ Wr, float* __restrict__ WRT) {
  int g = blockIdx.x*256 + threadIdx.x;
  if (g < N_HID*N_HID) {
    int j = g >> 9, r = g & 511;
    WRT[g] = Wr[r*N_HID + j];
  }
}
// NOTE: summation order of Srow/SOs is spike-determining — keep serial order exactly.
__global__ void k_prep_sums(const float* __restrict__ Wr, const float* __restrict__ Wo,
                            float* __restrict__ Srow, float* __restrict__ SOs,
                            int* __restrict__ tmax) {
  int g = blockIdx.x*256 + threadIdx.x;
  if (g < N_HID) {
    float s = 0.f;
    for (int j = 0; j < N_HID; ++j) s += Wr[g*N_HID + j];
    Srow[g] = s;
  } else if (g < N_HID + N_OUT) {
    int o = g - N_HID;
    float s = 0.f;
    for (int r = 0; r < N_HID; ++r) s += Wo[o*N_HID + r];
    SOs[o] = s;
  }
  if (g < BB) tmax[g] = 0;
}

// ---------------- phase A: INL = X @ (WH^T + WL^T), MFMA split-bf16 ----------------
__global__ __launch_bounds__(256) void k_gemm(const float* __restrict__ x,
                                              const unsigned short* __restrict__ WH,
                                              const unsigned short* __restrict__ WL,
                                              float* __restrict__ INL) {
  __shared__ __align__(16) unsigned short sA [128*32];
  __shared__ __align__(16) unsigned short sBh[128*32];
  __shared__ __align__(16) unsigned short sBl[128*32];
  const int tid = threadIdx.x, lane = tid & 63, w = tid >> 6;
  const int k0 = blockIdx.x * 128;
  const int c0 = blockIdx.y * 128;
  const int wr = w >> 1, wc = w & 1;
  const int fr = lane & 15, fk = lane >> 4;

  const int a_r  = tid >> 1;
  const int a_cb = (tid & 1) * 16;
  const int b_r  = tid >> 2;
  const int b_c  = (tid & 3) * 8;

  const float* xr = x + (size_t)(k0 + a_r) * N_IN;
  const unsigned short* gh = WH + (size_t)(c0 + b_r) * N_INP;
  const unsigned short* gl = WL + (size_t)(c0 + b_r) * N_INP;

  f32x4 acc[4][4];
  #pragma unroll
  for (int m = 0; m < 4; ++m)
    #pragma unroll
    for (int n = 0; n < 4; ++n)
      acc[m][n] = (f32x4){0.f, 0.f, 0.f, 0.f};

  for (int s = 0; s < N_INP/32; ++s) {
    const int i0 = s * 32;
    float av[16];
    const int col0 = i0 + a_cb;
    if (col0 + 16 <= N_IN) {
      float4 t0 = *(const float4*)(xr + col0);
      float4 t1 = *(const float4*)(xr + col0 + 4);
      float4 t2 = *(const float4*)(xr + col0 + 8);
      float4 t3 = *(const float4*)(xr + col0 + 12);
      av[0]=t0.x; av[1]=t0.y; av[2]=t0.z; av[3]=t0.w;
      av[4]=t1.x; av[5]=t1.y; av[6]=t1.z; av[7]=t1.w;
      av[8]=t2.x; av[9]=t2.y; av[10]=t2.z; av[11]=t2.w;
      av[12]=t3.x; av[13]=t3.y; av[14]=t3.z; av[15]=t3.w;
    } else {
      #pragma unroll
      for (int j = 0; j < 16; ++j) av[j] = (col0 + j < N_IN) ? xr[col0 + j] : 0.f;
    }
    uint32_t us[8];
    #pragma unroll
    for (int p = 0; p < 8; ++p) {
      uint32_t lo = __builtin_bit_cast(uint32_t, av[2*p])   >> 16;
      uint32_t hi = __builtin_bit_cast(uint32_t, av[2*p+1]) & 0xFFFF0000u;
      us[p] = hi | lo;
    }
    *(uint4*)&sA[a_r*32 + a_cb]     = make_uint4(us[0], us[1], us[2], us[3]);
    *(uint4*)&sA[a_r*32 + a_cb + 8] = make_uint4(us[4], us[5], us[6], us[7]);
    *(uint4*)&sBh[b_r*32 + b_c]      = *(const uint4*)(gh + i0 + b_c);
    *(uint4*)&sBh[(b_r+64)*32 + b_c] = *(const uint4*)(gh + (size_t)64*N_INP + i0 + b_c);
    *(uint4*)&sBl[b_r*32 + b_c]      = *(const uint4*)(gl + i0 + b_c);
    *(uint4*)&sBl[(b_r+64)*32 + b_c] = *(const uint4*)(gl + (size_t)64*N_INP + i0 + b_c);
    __syncthreads();

    bf16x8 a[4], bh[4], bl[4];
    #pragma unroll
    for (int m = 0; m < 4; ++m)
      a[m] = *(const bf16x8*)&sA[(wr*64 + m*16 + fr)*32 + fk*8];
    #pragma unroll
    for (int n = 0; n < 4; ++n) {
      bh[n] = *(const bf16x8*)&sBh[(wc*64 + n*16 + fr)*32 + fk*8];
      bl[n] = *(const bf16x8*)&sBl[(wc*64 + n*16 + fr)*32 + fk*8];
    }
    #pragma unroll
    for (int m = 0; m < 4; ++m)
      #pragma unroll
      for (int n = 0; n < 4; ++n) {
        acc[m][n] = __builtin_amdgcn_mfma_f32_16x16x32_bf16(a[m], bh[n], acc[m][n], 0, 0, 0);
        acc[m][n] = __builtin_amdgcn_mfma_f32_16x16x32_bf16(a[m], bl[n], acc[m][n], 0, 0, 0);
      }
    __syncthreads();
  }
  #pragma unroll
  for (int m = 0; m < 4; ++m) {
    #pragma unroll
    for (int n = 0; n < 4; ++n) {
      #pragma unroll
      for (int reg = 0; reg < 4; ++reg) {
        const int row = k0 + wr*64 + m*16 + (lane>>4)*4 + reg;
        const int col = c0 + wc*64 + n*16 + fr;
        INL[(size_t)row*N_HID + col] = acc[m][n][reg];
      }
    }
  }
}

// ---------------- phase B: scan; replicated out-state, reg-resident Wo, count-only exchange ----------------
__global__ __launch_bounds__(256) void k_scan(
    float* __restrict__ INL, const float* __restrict__ label,
    const float* __restrict__ Wo, const float* __restrict__ WRT,
    const float* __restrict__ Srow, const float* __restrict__ SOs,
    unsigned long long* __restrict__ hsbits, float* __restrict__ outs,
    float* __restrict__ pgo)
{
  const int b = blockIdx.x, tid = threadIdx.x;
  const int lane = tid & 63, w = tid >> 6;
  const int po = tid / 12, pc2 = tid - po*12;
  __shared__ float sWo[N_OUT*N_HID];              // 40 KB (slow path only)
  __shared__ int   list[N_HID];
  __shared__ __align__(16) int cint[2][8];
  __shared__ float part[N_OUT][13];
  __shared__ float compl_s[N_OUT];

  for (int idx = tid; idx < N_OUT*N_HID; idx += 256) sWo[idx] = Wo[idx];

  // per-thread register copies of Wo columns (read 100x per step otherwise)
  float woA[N_OUT], woB[N_OUT];
  #pragma unroll
  for (int o = 0; o < N_OUT; ++o) {
    woA[o] = Wo[o*N_HID + tid];
    woB[o] = Wo[o*N_HID + 256 + tid];
  }

  float hm0 = 0.f, hm1 = 0.f;
  int   hs0 = 0,   hs1 = 0;
  float tout0 = 0.f, tout1 = 0.f;
  float om[N_OUT], err[N_OUT], SOsr[N_OUT], go0[N_OUT], go1[N_OUT];
  uint32_t omask = 0;
  #pragma unroll
  for (int o = 0; o < N_OUT; ++o) { om[o] = 0.f; go0[o] = 0.f; go1[o] = 0.f; }
  {
    float4 s0v = *(const float4*)(SOs);
    float4 s1v = *(const float4*)(SOs + 4);
    float4 s2v = *(const float4*)(SOs + 8);
    float4 s3v = *(const float4*)(SOs + 12);
    float4 s4v = *(const float4*)(SOs + 16);
    SOsr[0]=s0v.x; SOsr[1]=s0v.y; SOsr[2]=s0v.z; SOsr[3]=s0v.w;
    SOsr[4]=s1v.x; SOsr[5]=s1v.y; SOsr[6]=s1v.z; SOsr[7]=s1v.w;
    SOsr[8]=s2v.x; SOsr[9]=s2v.y; SOsr[10]=s2v.z; SOsr[11]=s2v.w;
    SOsr[12]=s3v.x; SOsr[13]=s3v.y; SOsr[14]=s3v.z; SOsr[15]=s3v.w;
    SOsr[16]=s4v.x; SOsr[17]=s4v.y; SOsr[18]=s4v.z; SOsr[19]=s4v.w;
  }
  int cnt_prev = 0, mode_prev = 0;

  const size_t base = (size_t)b*TT;
  float in0 = INL[base*N_HID + tid];
  float in1 = INL[base*N_HID + 256 + tid];
  const float srow0 = Srow[tid], srow1 = Srow[256 + tid];
  __syncthreads();                                 // sWo ready

  for (int t = 0; t < TT; ++t) {
    const size_t k  = base + t;
    const size_t kn = (t < TT-1) ? (k + 1) : k;
    float4 l4[5];
    #pragma unroll
    for (int q = 0; q < 5; ++q) l4[q] = *(const float4*)(label + k*N_OUT + 4*q);
    const float nin0 = INL[kn*N_HID + tid];
    const float nin1 = INL[kn*N_HID + 256 + tid];

    float s0 = 0.f, s1 = 0.f;
    if (cnt_prev > 0) {                            // block-uniform
      for (int it = 0; it < cnt_prev; ++it) {
        const int j = list[it];
        s0 += WRT[j*N_HID + tid];
        s1 += WRT[j*N_HID + 256 + tid];
      }
    }
    const float rec0 = mode_prev ? (srow0 - s0) : s0;
    const float rec1 = mode_prev ? (srow1 - s1) : s1;

    const float nhm0 = TAU*hm0*(hs0 ? 0.f : 1.f) + in0 + rec0;
    const float nhm1 = TAU*hm1*(hs1 ? 0.f : 1.f) + in1 + rec1;
    const int nhs0 = (nhm0 >= THR) ? 1 : 0;
    const int nhs1 = (nhm1 >= THR) ? 1 : 0;

    const unsigned long long mA = __ballot(nhs0 != 0);
    const unsigned long long mB = __ballot(nhs1 != 0);
    const int p = t & 1;
    if (lane == 0) {
      cint[p][w]     = (int)__popcll(mA);
      cint[p][4 + w] = (int)__popcll(mB);
      hsbits[k*8 + w]     = mA;                    // wave-local, straight to global
      hsbits[k*8 + 4 + w] = mB;
    }
    __syncthreads();                               // the ONE fast-path barrier

    int4 ca = *(const int4*)&cint[p][0];
    int4 cb = *(const int4*)&cint[p][4];
    int pcs[8];
    pcs[0]=ca.x; pcs[1]=ca.y; pcs[2]=ca.z; pcs[3]=ca.w;
    pcs[4]=cb.x; pcs[5]=cb.y; pcs[6]=cb.z; pcs[7]=cb.w;
    const int ctot = pcs[0]+pcs[1]+pcs[2]+pcs[3]+pcs[4]+pcs[5]+pcs[6]+pcs[7];
    const int mode = (ctot <= 256) ? 0 : 1;
    int pre[8];
    pre[0] = 0;
    #pragma unroll
    for (int q = 1; q < 8; ++q) pre[q] = pre[q-1] + (mode ? 64 - pcs[q-1] : pcs[q-1]);
    const int cnt = pre[7] + (mode ? 64 - pcs[7] : pcs[7]);

    float gath[N_OUT];
    if (cnt != 0) {                                // slow path (~2 steps of 100), block-uniform
      {
        const unsigned long long below = (1ULL << lane) - 1ULL;
        const unsigned long long sm0 = mode ? ~mA : mA;
        const unsigned long long sm1 = mode ? ~mB : mB;
        if (mode ? !nhs0 : nhs0) list[pre[w]     + (int)__popcll(sm0 & below)] = tid;
        if (mode ? !nhs1 : nhs1) list[pre[4 + w] + (int)__popcll(sm1 & below)] = tid + 256;
      }
      __syncthreads();
      if (tid < 240) {
        float s = 0.f;
        for (int it = pc2; it < cnt; it += 12) s += sWo[po*N_HID + list[it]];
        part[po][pc2] = s;
      }
      __syncthreads();
      if (tid < N_OUT) {
        float dsum = 0.f;
        #pragma unroll
        for (int c2 = 0; c2 < 12; ++c2) dsum += part[tid][c2];
        compl_s[tid] = dsum;
      }
      __syncthreads();
      #pragma unroll
      for (int o = 0; o < N_OUT; ++o) gath[o] = compl_s[o];
    } else {
      #pragma unroll
      for (int o = 0; o < N_OUT; ++o) gath[o] = 0.f;
    }

    // replicated output-neuron update (identical FP sequence in every thread)
    float la[N_OUT];
    #pragma unroll
    for (int q = 0; q < 5; ++q) {
      la[4*q+0] = l4[q].x; la[4*q+1] = l4[q].y; la[4*q+2] = l4[q].z; la[4*q+3] = l4[q].w;
    }
    uint32_t nosmask = 0;
    #pragma unroll
    for (int o = 0; o < N_OUT; ++o) {
      const float drive = mode ? (SOsr[o] - gath[o]) : gath[o];
      om[o] = TAU*om[o]*(((omask >> o) & 1u) ? 0.f : 1.f) + drive;
      const int nos = (om[o] >= THR) ? 1 : 0;
      nosmask |= ((uint32_t)nos) << o;
      err[o] = (nos ? 1.f : 0.f) - la[o];
    }
    omask = nosmask;
    if (tid < N_OUT) outs[k*N_OUT + tid] = (float)((nosmask >> tid) & 1u);

    // d = err . Wo  — pure register FMAs, no branches, no LDS
    float d0 = 0.f, d1 = 0.f;
    #pragma unroll
    for (int o = 0; o < N_OUT; ++o) {
      d0 += err[o] * woA[o];
      d1 += err[o] * woB[o];
    }
    const float a0f = fabsf(nhm0 - THR) / THR;
    const float a1f = fabsf(nhm1 - THR) / THR;
    const float ht0 = GAM * fmaxf(0.f, 1.f - a0f);
    const float ht1 = GAM * fmaxf(0.f, 1.f - a1f);
    INL[k*N_HID + tid]       = d0 * ht0;
    INL[k*N_HID + 256 + tid] = d1 * ht1;

    tout0 = TAU_O*tout0 + (nhs0 ? 1.f : 0.f);
    tout1 = TAU_O*tout1 + (nhs1 ? 1.f : 0.f);
    #pragma unroll
    for (int o = 0; o < N_OUT; ++o) {
      go0[o] += err[o] * tout0;
      go1[o] += err[o] * tout1;
    }

    hm0 = nhm0; hm1 = nhm1; hs0 = nhs0; hs1 = nhs1;
    cnt_prev = cnt; mode_prev = mode;
    in0 = nin0; in1 = nin1;
  }
  #pragma unroll
  for (int o = 0; o < N_OUT; ++o) {
    pgo[((size_t)b*N_OUT + o)*N_HID + tid]       = go0[o];
    pgo[((size_t)b*N_OUT + o)*N_HID + 256 + tid] = go1[o];
  }
}

// ---------------- phase C: reverse filter with 1-deep prefetch ----------------
__global__ void k_mfilter(float* __restrict__ L, int* __restrict__ tmax) {
  const int g = blockIdx.x*256 + threadIdx.x;   // (b, r)
  const int b = g >> 9, r = g & 511;
  const size_t rowbase = (size_t)b*TT;
  float m = 0.f;
  int last = -1;
  float cur = L[(rowbase + TT - 1)*N_HID + r];
  for (int t = TT - 1; t >= 0; --t) {
    const float nxt = (t > 0) ? L[(rowbase + t - 1)*N_HID + r] : 0.f;
    const float v = cur + TAU*m;
    L[(rowbase + t)*N_HID + r] = v;
    m = v;
    if (v != 0.f && last < 0) last = t;
    cur = nxt;
  }
  if (last >= 0) atomicMax(tmax + b, last + 1);
}

// ---------------- phase D: go = 0.1 * sum_b pgo[b]  (160 blocks, 4-way b-split, ordered reduce) ----------------
__global__ __launch_bounds__(256) void k_go(const float* __restrict__ pgo, float* __restrict__ go) {
  __shared__ float red[4][64];
  const int l = threadIdx.x & 63;
  const int ch = threadIdx.x >> 6;
  const int col = blockIdx.x*64 + l;
  float s = 0.f;
  for (int b2 = ch*64; b2 < ch*64 + 64; ++b2)
    s += pgo[(size_t)b2*(N_OUT*N_HID) + col];
  red[ch][l] = s;
  __syncthreads();
  if (ch == 0) go[col] = 0.1f*(((red[0][l] + red[1][l]) + red[2][l]) + red[3][l]);
}

// ---------------- phase D: gf partials over b-chunks ----------------
__global__ __launch_bounds__(256) void k_gf(const float* __restrict__ M, const float* __restrict__ x,
                                            const int* __restrict__ tmax,
                                            float* __restrict__ gfp) {
  const int lane = threadIdx.x & 63, w = threadIdx.x >> 6;
  const int r  = blockIdx.x*64 + lane;
  const int i0 = blockIdx.y*64 + w*16;
  const int ch = blockIdx.z;
  const int b_lo = ch * (BB/NCH);
  __shared__ int cnt_sh[BB/NCH];
  if (threadIdx.x < BB/NCH) cnt_sh[threadIdx.x] = tmax[b_lo + threadIdx.x];
  __syncthreads();
  float acc[16];
  #pragma unroll
  for (int ii = 0; ii < 16; ++ii) acc[ii] = 0.f;
  int xi = i0 + (lane & 15); if (xi > N_IN - 1) xi = N_IN - 1;
  for (int bi = 0; bi < BB/NCH; ++bi) {
    const int ct = cnt_sh[bi];
    if (ct == 0) continue;
    const size_t kb = (size_t)(b_lo + bi)*TT;
    float mv = M[kb*N_HID + r];
    float xv = x[kb*N_IN + xi];
    for (int t = 0; t < ct; ++t) {
      float mv_n = 0.f, xv_n = 0.f;
      if (t + 1 < ct) {
        mv_n = M[(kb + t + 1)*N_HID + r];
        xv_n = x[(kb + t + 1)*N_IN + xi];
      }
      #pragma unroll
      for (int ii = 0; ii < 16; ++ii) acc[ii] += mv * __shfl(xv, ii);
      mv = mv_n; xv = xv_n;
    }
  }
  #pragma unroll
  for (int ii = 0; ii < 16; ++ii) {
    const int i = i0 + ii;
    if (i < N_IN) gfp[(size_t)ch*(N_HID*N_IN) + (size_t)r*N_IN + i] = acc[ii];
  }
}

// ---------------- phase D: gr partials over b-chunks ----------------
__global__ __launch_bounds__(256) void k_gr(const float* __restrict__ M,
                                            const unsigned long long* __restrict__ hsbits,
                                            const int* __restrict__ tmax,
                                            float* __restrict__ grp) {
  const int lane = threadIdx.x & 63, w = threadIdx.x >> 6;
  const int r  = blockIdx.x*64 + lane;
  const int h0 = blockIdx.y*64 + w*16;
  const int ch = blockIdx.z;
  const int b_lo = ch * (BB/NCH);
  __shared__ int cnt_sh[BB/NCH];
  if (threadIdx.x < BB/NCH) cnt_sh[threadIdx.x] = tmax[b_lo + threadIdx.x];
  __syncthreads();
  float acc[16];
  #pragma unroll
  for (int ii = 0; ii < 16; ++ii) acc[ii] = 0.f;
  const int hw = h0 >> 6, sh = h0 & 63;
  for (int bi = 0; bi < BB/NCH; ++bi) {
    const int ct = cnt_sh[bi];
    if (ct == 0) continue;
    const size_t kb = (size_t)(b_lo + bi)*TT;
    float mv = M[kb*N_HID + r];
    unsigned long long word = hsbits[kb*8 + hw];
    for (int t = 0; t < ct; ++t) {
      float mv_n = 0.f; unsigned long long word_n = 0ULL;
      if (t + 1 < ct) {
        mv_n = M[(kb + t + 1)*N_HID + r];
        word_n = hsbits[(kb + t + 1)*8 + hw];
      }
      #pragma unroll
      for (int ii = 0; ii < 16; ++ii)
        if ((word >> (sh + ii)) & 1ULL) acc[ii] += mv;
      mv = mv_n; word = word_n;
    }
  }
  #pragma unroll
  for (int ii = 0; ii < 16; ++ii)
    grp[(size_t)ch*(N_HID*N_HID) + (size_t)r*N_HID + h0 + ii] = acc[ii];
}

// ---------------- phase D: deterministic partial reductions ----------------
__global__ void k_gfred(const float* __restrict__ gfp, float* __restrict__ gf) {
  const int g = blockIdx.x*256 + threadIdx.x;
  if (g < N_HID*N_IN) {
    float s = 0.f;
    #pragma unroll
    for (int c = 0; c < NCH; ++c) s += gfp[(size_t)c*(N_HID*N_IN) + g];
    gf[g] = 0.1f*s;
  }
}
__global__ void k_grred(const float* __restrict__ grp, float* __restrict__ gr) {
  const int g = blockIdx.x*256 + threadIdx.x;
  if (g < N_HID*N_HID) {
    float s = 0.f;
    #pragma unroll
    for (int c = 0; c < NCH; ++c) s += grp[(size_t)c*(N_HID*N_HID) + g];
    gr[g] = 0.1f*s;
  }
}

extern "C" void kernel_launch(void* const* d_in, const int* in_sizes, int n_in,
                              void* d_out, int out_size, void* d_ws, size_t ws_size,
                              hipStream_t stream) {
  const float* x     = (const float*)d_in[0];
  const float* label = (const float*)d_in[1];
  const float* W1    = (const float*)d_in[2];
  const float* Wr    = (const float*)d_in[3];
  const float* Wo    = (const float*)d_in[4];

  float* out  = (float*)d_out;
  float* outs = out;                                    // [256][100][20]
  float* gf   = out + 512000;                           // [512][700]
  float* gr   = out + 512000 + 358400;                  // [512][512]
  float* go   = out + 512000 + 358400 + 262144;         // [20][512]

  char* ws = (char*)d_ws;
  size_t off = 0;
  auto alloc = [&](size_t bytes) -> char* {
    char* p = ws + off;
    off += (bytes + 255) & ~(size_t)255;
    return p;
  };
  float* INL = (float*)alloc((size_t)NK*N_HID*sizeof(float));                    // 52.43 MB
  unsigned long long* hsb = (unsigned long long*)alloc((size_t)NK*8*sizeof(unsigned long long)); // 1.64 MB
  int* tmax = (int*)alloc((size_t)BB*sizeof(int));
  char* uni = alloc((size_t)20971520);                                           // 20 MB union region

  // early residents of uni (dead after k_go)
  unsigned short* WH = (unsigned short*)(uni);                                   // 0.72 MB
  unsigned short* WL = (unsigned short*)(uni + 720896);                          // 0.72 MB
  float* WRT  = (float*)(uni + 2*720896);                                        // 1.05 MB
  float* Srow = (float*)(uni + 2*720896 + 1048576);
  float* SOs  = (float*)(uni + 2*720896 + 1048576 + 2048);
  float* pgo  = (float*)(uni + 2*720896 + 1048576 + 4096);                       // 10.49 MB
  // late residents of uni (written only after k_go has consumed pgo)
  float* gfp  = (float*)(uni);                                                   // 11.47 MB
  float* grp  = (float*)(uni + (size_t)NCH*N_HID*N_IN*sizeof(float));            // 8.39 MB

  k_wsplit<<<(N_HID*88 + 255)/256, 256, 0, stream>>>(W1, WH, WL);
  k_prep_t2<<<(N_HID*N_HID + 255)/256, 256, 0, stream>>>(Wr, WRT);
  k_prep_sums<<<(N_HID + N_OUT + 255)/256, 256, 0, stream>>>(Wr, Wo, Srow, SOs, tmax);
  dim3 gg(NK/128, N_HID/128);
  k_gemm<<<gg, 256, 0, stream>>>(x, WH, WL, INL);
  k_scan<<<BB, 256, 0, stream>>>(INL, label, Wo, WRT, Srow, SOs, hsb, outs, pgo);
  k_mfilter<<<(BB*N_HID)/256, 256, 0, stream>>>(INL, tmax);
  k_go<<<(N_OUT*N_HID)/64, 256, 0, stream>>>(pgo, go);
  dim3 ggf(8, 11, NCH); k_gf<<<ggf, 256, 0, stream>>>(INL, x, tmax, gfp);
  dim3 ggr(8, 8, NCH);  k_gr<<<ggr, 256, 0, stream>>>(INL, hsb, tmax, grp);
  k_gfred<<<(N_HID*N_IN + 255)/256, 256, 0, stream>>>(gfp, gf);
  k_grred<<<(N_HID*N_HID + 255)/256, 256, 0, stream>>>(grp, gr);
}

// Round 7
// 535.591 us; speedup vs baseline: 1.0995x; 1.0026x over previous
//
#include <hip/hip_runtime.h>
#include <cstdint>
#include <cstddef>

#define N_IN  700
#define N_INP 704           // K padded to 32
#define N_HID 512
#define N_OUT 20
#define BB    256
#define TT    100
#define NK    (BB*TT)       // 25600
#define NCH   8             // split-k chunks for gf/gr

__device__ __constant__ const float TAU   = 0.6f;
__device__ __constant__ const float TAU_O = 0.6f;
__device__ __constant__ const float THR   = 0.6f;
__device__ __constant__ const float GAM   = 0.3f;

typedef float f32x4 __attribute__((ext_vector_type(4)));
typedef __bf16 bf16x8 __attribute__((ext_vector_type(8)));

__device__ __forceinline__ unsigned short f2bf_rne(float f) {
  uint32_t b = __builtin_bit_cast(uint32_t, f);
  uint32_t r = (b + 0x7FFFu + ((b >> 16) & 1u)) >> 16;
  return (unsigned short)r;
}
__device__ __forceinline__ float bf2f(unsigned short u) {
  uint32_t b = ((uint32_t)u) << 16;
  return __builtin_bit_cast(float, b);
}

// lgkm-only barrier: orders LDS exchange without draining global loads/stores.
// (HIP __syncthreads emits s_waitcnt vmcnt(0) lgkmcnt(0) — the vmcnt drain is
// the ~4000 cy/step stall observed in r6.)
__device__ __forceinline__ void barrier_lgkm() {
  asm volatile("s_waitcnt lgkmcnt(0)" ::: "memory");
  __builtin_amdgcn_s_barrier();
  __builtin_amdgcn_sched_barrier(0);
}

// ---------------- prep: W split into hi+lo bf16, [r][i] layout padded to 704 ----------------
__global__ void k_wsplit(const float* __restrict__ W1,
                         unsigned short* __restrict__ WH,
                         unsigned short* __restrict__ WL) {
  int g = blockIdx.x*256 + threadIdx.x;
  if (g >= N_HID*88) return;
  int r = g / 88, c = g - (g/88)*88;
  int ib = c*8;
  unsigned short h[8], l[8];
  #pragma unroll
  for (int j = 0; j < 8; ++j) {
    int i = ib + j;
    float v = (i < N_IN) ? W1[r*N_IN + i] : 0.f;
    unsigned short hh = f2bf_rne(v);
    float res = v - bf2f(hh);
    h[j] = hh;
    l[j] = f2bf_rne(res);
  }
  uint4 hv = make_uint4((uint32_t)h[0] | ((uint32_t)h[1]<<16), (uint32_t)h[2] | ((uint32_t)h[3]<<16),
                        (uint32_t)h[4] | ((uint32_t)h[5]<<16), (uint32_t)h[6] | ((uint32_t)h[7]<<16));
  uint4 lv = make_uint4((uint32_t)l[0] | ((uint32_t)l[1]<<16), (uint32_t)l[2] | ((uint32_t)l[3]<<16),
                        (uint32_t)l[4] | ((uint32_t)l[5]<<16), (uint32_t)l[6] | ((uint32_t)l[7]<<16));
  *(uint4*)(WH + (size_t)r*N_INP + ib) = hv;
  *(uint4*)(WL + (size_t)r*N_INP + ib) = lv;
}

__global__ void k_prep_t2(const float* __restrict__ Wr, float* __restrict__ WRT) {
  int g = blockIdx.x*256 + threadIdx.x;
  if (g < N_HID*N_HID) {
    int j = g >> 9, r = g & 511;
    WRT[g] = Wr[r*N_HID + j];
  }
}
// NOTE: summation order of Srow/SOs is spike-determining — keep serial order exactly.
__global__ void k_prep_sums(const float* __restrict__ Wr, const float* __restrict__ Wo,
                            float* __restrict__ Srow, float* __restrict__ SOs,
                            int* __restrict__ tmax) {
  int g = blockIdx.x*256 + threadIdx.x;
  if (g < N_HID) {
    float s = 0.f;
    for (int j = 0; j < N_HID; ++j) s += Wr[g*N_HID + j];
    Srow[g] = s;
  } else if (g < N_HID + N_OUT) {
    int o = g - N_HID;
    float s = 0.f;
    for (int r = 0; r < N_HID; ++r) s += Wo[o*N_HID + r];
    SOs[o] = s;
  }
  if (g < BB) tmax[g] = 0;
}

// ---------------- phase A: INL = X @ (WH^T + WL^T), MFMA split-bf16 ----------------
__global__ __launch_bounds__(256) void k_gemm(const float* __restrict__ x,
                                              const unsigned short* __restrict__ WH,
                                              const unsigned short* __restrict__ WL,
                                              float* __restrict__ INL) {
  __shared__ __align__(16) unsigned short sA [128*32];
  __shared__ __align__(16) unsigned short sBh[128*32];
  __shared__ __align__(16) unsigned short sBl[128*32];
  const int tid = threadIdx.x, lane = tid & 63, w = tid >> 6;
  const int k0 = blockIdx.x * 128;
  const int c0 = blockIdx.y * 128;
  const int wr = w >> 1, wc = w & 1;
  const int fr = lane & 15, fk = lane >> 4;

  const int a_r  = tid >> 1;
  const int a_cb = (tid & 1) * 16;
  const int b_r  = tid >> 2;
  const int b_c  = (tid & 3) * 8;

  const float* xr = x + (size_t)(k0 + a_r) * N_IN;
  const unsigned short* gh = WH + (size_t)(c0 + b_r) * N_INP;
  const unsigned short* gl = WL + (size_t)(c0 + b_r) * N_INP;

  f32x4 acc[4][4];
  #pragma unroll
  for (int m = 0; m < 4; ++m)
    #pragma unroll
    for (int n = 0; n < 4; ++n)
      acc[m][n] = (f32x4){0.f, 0.f, 0.f, 0.f};

  for (int s = 0; s < N_INP/32; ++s) {
    const int i0 = s * 32;
    float av[16];
    const int col0 = i0 + a_cb;
    if (col0 + 16 <= N_IN) {
      float4 t0 = *(const float4*)(xr + col0);
      float4 t1 = *(const float4*)(xr + col0 + 4);
      float4 t2 = *(const float4*)(xr + col0 + 8);
      float4 t3 = *(const float4*)(xr + col0 + 12);
      av[0]=t0.x; av[1]=t0.y; av[2]=t0.z; av[3]=t0.w;
      av[4]=t1.x; av[5]=t1.y; av[6]=t1.z; av[7]=t1.w;
      av[8]=t2.x; av[9]=t2.y; av[10]=t2.z; av[11]=t2.w;
      av[12]=t3.x; av[13]=t3.y; av[14]=t3.z; av[15]=t3.w;
    } else {
      #pragma unroll
      for (int j = 0; j < 16; ++j) av[j] = (col0 + j < N_IN) ? xr[col0 + j] : 0.f;
    }
    uint32_t us[8];
    #pragma unroll
    for (int p = 0; p < 8; ++p) {
      uint32_t lo = __builtin_bit_cast(uint32_t, av[2*p])   >> 16;
      uint32_t hi = __builtin_bit_cast(uint32_t, av[2*p+1]) & 0xFFFF0000u;
      us[p] = hi | lo;
    }
    *(uint4*)&sA[a_r*32 + a_cb]     = make_uint4(us[0], us[1], us[2], us[3]);
    *(uint4*)&sA[a_r*32 + a_cb + 8] = make_uint4(us[4], us[5], us[6], us[7]);
    *(uint4*)&sBh[b_r*32 + b_c]      = *(const uint4*)(gh + i0 + b_c);
    *(uint4*)&sBh[(b_r+64)*32 + b_c] = *(const uint4*)(gh + (size_t)64*N_INP + i0 + b_c);
    *(uint4*)&sBl[b_r*32 + b_c]      = *(const uint4*)(gl + i0 + b_c);
    *(uint4*)&sBl[(b_r+64)*32 + b_c] = *(const uint4*)(gl + (size_t)64*N_INP + i0 + b_c);
    __syncthreads();

    bf16x8 a[4], bh[4], bl[4];
    #pragma unroll
    for (int m = 0; m < 4; ++m)
      a[m] = *(const bf16x8*)&sA[(wr*64 + m*16 + fr)*32 + fk*8];
    #pragma unroll
    for (int n = 0; n < 4; ++n) {
      bh[n] = *(const bf16x8*)&sBh[(wc*64 + n*16 + fr)*32 + fk*8];
      bl[n] = *(const bf16x8*)&sBl[(wc*64 + n*16 + fr)*32 + fk*8];
    }
    #pragma unroll
    for (int m = 0; m < 4; ++m)
      #pragma unroll
      for (int n = 0; n < 4; ++n) {
        acc[m][n] = __builtin_amdgcn_mfma_f32_16x16x32_bf16(a[m], bh[n], acc[m][n], 0, 0, 0);
        acc[m][n] = __builtin_amdgcn_mfma_f32_16x16x32_bf16(a[m], bl[n], acc[m][n], 0, 0, 0);
      }
    __syncthreads();
  }
  #pragma unroll
  for (int m = 0; m < 4; ++m) {
    #pragma unroll
    for (int n = 0; n < 4; ++n) {
      #pragma unroll
      for (int reg = 0; reg < 4; ++reg) {
        const int row = k0 + wr*64 + m*16 + (lane>>4)*4 + reg;
        const int col = c0 + wc*64 + n*16 + fr;
        INL[(size_t)row*N_HID + col] = acc[m][n][reg];
      }
    }
  }
}

// ---------------- phase B: scan; replicated out-state, reg Wo, lgkm-only fast-path barrier ----------------
__global__ __launch_bounds__(256) void k_scan(
    float* __restrict__ INL, const float* __restrict__ label,
    const float* __restrict__ Wo, const float* __restrict__ WRT,
    const float* __restrict__ Srow, const float* __restrict__ SOs,
    unsigned long long* __restrict__ hsbits, float* __restrict__ outs,
    float* __restrict__ pgo)
{
  const int b = blockIdx.x, tid = threadIdx.x;
  const int lane = tid & 63, w = tid >> 6;
  const int po = tid / 12, pc2 = tid - po*12;
  __shared__ float sWo[N_OUT*N_HID];              // 40 KB (slow path only)
  __shared__ int   list[N_HID];
  __shared__ __align__(16) int cint[2][8];
  __shared__ float part[N_OUT][13];
  __shared__ float compl_s[N_OUT];

  for (int idx = tid; idx < N_OUT*N_HID; idx += 256) sWo[idx] = Wo[idx];

  // per-thread register copies of Wo columns
  float woA[N_OUT], woB[N_OUT];
  #pragma unroll
  for (int o = 0; o < N_OUT; ++o) {
    woA[o] = Wo[o*N_HID + tid];
    woB[o] = Wo[o*N_HID + 256 + tid];
  }

  float hm0 = 0.f, hm1 = 0.f;
  int   hs0 = 0,   hs1 = 0;
  float tout0 = 0.f, tout1 = 0.f;
  float om[N_OUT], err[N_OUT], SOsr[N_OUT], go0[N_OUT], go1[N_OUT];
  uint32_t omask = 0;
  #pragma unroll
  for (int o = 0; o < N_OUT; ++o) { om[o] = 0.f; go0[o] = 0.f; go1[o] = 0.f; }
  {
    float4 s0v = *(const float4*)(SOs);
    float4 s1v = *(const float4*)(SOs + 4);
    float4 s2v = *(const float4*)(SOs + 8);
    float4 s3v = *(const float4*)(SOs + 12);
    float4 s4v = *(const float4*)(SOs + 16);
    SOsr[0]=s0v.x; SOsr[1]=s0v.y; SOsr[2]=s0v.z; SOsr[3]=s0v.w;
    SOsr[4]=s1v.x; SOsr[5]=s1v.y; SOsr[6]=s1v.z; SOsr[7]=s1v.w;
    SOsr[8]=s2v.x; SOsr[9]=s2v.y; SOsr[10]=s2v.z; SOsr[11]=s2v.w;
    SOsr[12]=s3v.x; SOsr[13]=s3v.y; SOsr[14]=s3v.z; SOsr[15]=s3v.w;
    SOsr[16]=s4v.x; SOsr[17]=s4v.y; SOsr[18]=s4v.z; SOsr[19]=s4v.w;
  }
  int cnt_prev = 0, mode_prev = 0;

  const size_t base = (size_t)b*TT;
  float in0 = INL[base*N_HID + tid];
  float in1 = INL[base*N_HID + 256 + tid];
  const float srow0 = Srow[tid], srow1 = Srow[256 + tid];
  __syncthreads();                                 // sWo ready (full barrier once)

  for (int t = 0; t < TT; ++t) {
    const size_t k  = base + t;
    const size_t kn = (t < TT-1) ? (k + 1) : k;
    float4 l4[5];
    #pragma unroll
    for (int q = 0; q < 5; ++q) l4[q] = *(const float4*)(label + k*N_OUT + 4*q);
    const float nin0 = INL[kn*N_HID + tid];
    const float nin1 = INL[kn*N_HID + 256 + tid];

    float s0 = 0.f, s1 = 0.f;
    if (cnt_prev > 0) {                            // block-uniform
      for (int it = 0; it < cnt_prev; ++it) {
        const int j = list[it];
        s0 += WRT[j*N_HID + tid];
        s1 += WRT[j*N_HID + 256 + tid];
      }
    }
    const float rec0 = mode_prev ? (srow0 - s0) : s0;
    const float rec1 = mode_prev ? (srow1 - s1) : s1;

    const float nhm0 = TAU*hm0*(hs0 ? 0.f : 1.f) + in0 + rec0;
    const float nhm1 = TAU*hm1*(hs1 ? 0.f : 1.f) + in1 + rec1;
    const int nhs0 = (nhm0 >= THR) ? 1 : 0;
    const int nhs1 = (nhm1 >= THR) ? 1 : 0;

    const unsigned long long mA = __ballot(nhs0 != 0);
    const unsigned long long mB = __ballot(nhs1 != 0);
    const int p = t & 1;
    if (lane == 0) {
      cint[p][w]     = (int)__popcll(mA);
      cint[p][4 + w] = (int)__popcll(mB);
      hsbits[k*8 + w]     = mA;                    // wave-local, straight to global
      hsbits[k*8 + 4 + w] = mB;
    }
    barrier_lgkm();                                // the ONE fast-path barrier (no vmcnt drain)

    int4 ca = *(const int4*)&cint[p][0];
    int4 cb = *(const int4*)&cint[p][4];
    int pcs[8];
    pcs[0]=ca.x; pcs[1]=ca.y; pcs[2]=ca.z; pcs[3]=ca.w;
    pcs[4]=cb.x; pcs[5]=cb.y; pcs[6]=cb.z; pcs[7]=cb.w;
    const int ctot = pcs[0]+pcs[1]+pcs[2]+pcs[3]+pcs[4]+pcs[5]+pcs[6]+pcs[7];
    const int mode = (ctot <= 256) ? 0 : 1;
    const int cnt  = mode ? (512 - ctot) : ctot;

    float gath[N_OUT];
    if (cnt != 0) {                                // slow path (~2 steps of 100), block-uniform
      int pre[8];
      pre[0] = 0;
      #pragma unroll
      for (int q = 1; q < 8; ++q) pre[q] = pre[q-1] + (mode ? 64 - pcs[q-1] : pcs[q-1]);
      {
        const unsigned long long below = (1ULL << lane) - 1ULL;
        const unsigned long long sm0 = mode ? ~mA : mA;
        const unsigned long long sm1 = mode ? ~mB : mB;
        if (mode ? !nhs0 : nhs0) list[pre[w]     + (int)__popcll(sm0 & below)] = tid;
        if (mode ? !nhs1 : nhs1) list[pre[4 + w] + (int)__popcll(sm1 & below)] = tid + 256;
      }
      __syncthreads();
      if (tid < 240) {
        float s = 0.f;
        for (int it = pc2; it < cnt; it += 12) s += sWo[po*N_HID + list[it]];
        part[po][pc2] = s;
      }
      __syncthreads();
      if (tid < N_OUT) {
        float dsum = 0.f;
        #pragma unroll
        for (int c2 = 0; c2 < 12; ++c2) dsum += part[tid][c2];
        compl_s[tid] = dsum;
      }
      __syncthreads();
      #pragma unroll
      for (int o = 0; o < N_OUT; ++o) gath[o] = compl_s[o];
    } else {
      #pragma unroll
      for (int o = 0; o < N_OUT; ++o) gath[o] = 0.f;
    }

    // replicated output-neuron update (identical FP sequence in every thread)
    float la[N_OUT];
    #pragma unroll
    for (int q = 0; q < 5; ++q) {
      la[4*q+0] = l4[q].x; la[4*q+1] = l4[q].y; la[4*q+2] = l4[q].z; la[4*q+3] = l4[q].w;
    }
    uint32_t nosmask = 0;
    #pragma unroll
    for (int o = 0; o < N_OUT; ++o) {
      const float drive = mode ? (SOsr[o] - gath[o]) : gath[o];
      om[o] = TAU*om[o]*(((omask >> o) & 1u) ? 0.f : 1.f) + drive;
      const int nos = (om[o] >= THR) ? 1 : 0;
      nosmask |= ((uint32_t)nos) << o;
      err[o] = (nos ? 1.f : 0.f) - la[o];
    }
    omask = nosmask;
    if (tid < N_OUT) outs[k*N_OUT + tid] = (float)((nosmask >> tid) & 1u);

    // d = err . Wo  — pure register FMAs
    float d0 = 0.f, d1 = 0.f;
    #pragma unroll
    for (int o = 0; o < N_OUT; ++o) {
      d0 += err[o] * woA[o];
      d1 += err[o] * woB[o];
    }
    const float a0f = fabsf(nhm0 - THR) / THR;
    const float a1f = fabsf(nhm1 - THR) / THR;
    const float ht0 = GAM * fmaxf(0.f, 1.f - a0f);
    const float ht1 = GAM * fmaxf(0.f, 1.f - a1f);
    INL[k*N_HID + tid]       = d0 * ht0;
    INL[k*N_HID + 256 + tid] = d1 * ht1;

    tout0 = TAU_O*tout0 + (nhs0 ? 1.f : 0.f);
    tout1 = TAU_O*tout1 + (nhs1 ? 1.f : 0.f);
    #pragma unroll
    for (int o = 0; o < N_OUT; ++o) {
      go0[o] += err[o] * tout0;
      go1[o] += err[o] * tout1;
    }

    hm0 = nhm0; hm1 = nhm1; hs0 = nhs0; hs1 = nhs1;
    cnt_prev = cnt; mode_prev = mode;
    in0 = nin0; in1 = nin1;
  }
  #pragma unroll
  for (int o = 0; o < N_OUT; ++o) {
    pgo[((size_t)b*N_OUT + o)*N_HID + tid]       = go0[o];
    pgo[((size_t)b*N_OUT + o)*N_HID + 256 + tid] = go1[o];
  }
}

// ---------------- phase C: reverse filter with 1-deep prefetch ----------------
__global__ void k_mfilter(float* __restrict__ L, int* __restrict__ tmax) {
  const int g = blockIdx.x*256 + threadIdx.x;   // (b, r)
  const int b = g >> 9, r = g & 511;
  const size_t rowbase = (size_t)b*TT;
  float m = 0.f;
  int last = -1;
  float cur = L[(rowbase + TT - 1)*N_HID + r];
  for (int t = TT - 1; t >= 0; --t) {
    const float nxt = (t > 0) ? L[(rowbase + t - 1)*N_HID + r] : 0.f;
    const float v = cur + TAU*m;
    L[(rowbase + t)*N_HID + r] = v;
    m = v;
    if (v != 0.f && last < 0) last = t;
    cur = nxt;
  }
  if (last >= 0) atomicMax(tmax + b, last + 1);
}

// ---------------- phase D: go = 0.1 * sum_b pgo[b]  (160 blocks, 4-way b-split, ordered reduce) ----------------
__global__ __launch_bounds__(256) void k_go(const float* __restrict__ pgo, float* __restrict__ go) {
  __shared__ float red[4][64];
  const int l = threadIdx.x & 63;
  const int ch = threadIdx.x >> 6;
  const int col = blockIdx.x*64 + l;
  float s = 0.f;
  for (int b2 = ch*64; b2 < ch*64 + 64; ++b2)
    s += pgo[(size_t)b2*(N_OUT*N_HID) + col];
  red[ch][l] = s;
  __syncthreads();
  if (ch == 0) go[col] = 0.1f*(((red[0][l] + red[1][l]) + red[2][l]) + red[3][l]);
}

// ---------------- phase D: gf partials over b-chunks ----------------
__global__ __launch_bounds__(256) void k_gf(const float* __restrict__ M, const float* __restrict__ x,
                                            const int* __restrict__ tmax,
                                            float* __restrict__ gfp) {
  const int lane = threadIdx.x & 63, w = threadIdx.x >> 6;
  const int r  = blockIdx.x*64 + lane;
  const int i0 = blockIdx.y*64 + w*16;
  const int ch = blockIdx.z;
  const int b_lo = ch * (BB/NCH);
  __shared__ int cnt_sh[BB/NCH];
  if (threadIdx.x < BB/NCH) cnt_sh[threadIdx.x] = tmax[b_lo + threadIdx.x];
  __syncthreads();
  float acc[16];
  #pragma unroll
  for (int ii = 0; ii < 16; ++ii) acc[ii] = 0.f;
  int xi = i0 + (lane & 15); if (xi > N_IN - 1) xi = N_IN - 1;
  for (int bi = 0; bi < BB/NCH; ++bi) {
    const int ct = cnt_sh[bi];
    if (ct == 0) continue;
    const size_t kb = (size_t)(b_lo + bi)*TT;
    float mv = M[kb*N_HID + r];
    float xv = x[kb*N_IN + xi];
    for (int t = 0; t < ct; ++t) {
      float mv_n = 0.f, xv_n = 0.f;
      if (t + 1 < ct) {
        mv_n = M[(kb + t + 1)*N_HID + r];
        xv_n = x[(kb + t + 1)*N_IN + xi];
      }
      #pragma unroll
      for (int ii = 0; ii < 16; ++ii) acc[ii] += mv * __shfl(xv, ii);
      mv = mv_n; xv = xv_n;
    }
  }
  #pragma unroll
  for (int ii = 0; ii < 16; ++ii) {
    const int i = i0 + ii;
    if (i < N_IN) gfp[(size_t)ch*(N_HID*N_IN) + (size_t)r*N_IN + i] = acc[ii];
  }
}

// ---------------- phase D: gr partials over b-chunks ----------------
__global__ __launch_bounds__(256) void k_gr(const float* __restrict__ M,
                                            const unsigned long long* __restrict__ hsbits,
                                            const int* __restrict__ tmax,
                                            float* __restrict__ grp) {
  const int lane = threadIdx.x & 63, w = threadIdx.x >> 6;
  const int r  = blockIdx.x*64 + lane;
  const int h0 = blockIdx.y*64 + w*16;
  const int ch = blockIdx.z;
  const int b_lo = ch * (BB/NCH);
  __shared__ int cnt_sh[BB/NCH];
  if (threadIdx.x < BB/NCH) cnt_sh[threadIdx.x] = tmax[b_lo + threadIdx.x];
  __syncthreads();
  float acc[16];
  #pragma unroll
  for (int ii = 0; ii < 16; ++ii) acc[ii] = 0.f;
  const int hw = h0 >> 6, sh = h0 & 63;
  for (int bi = 0; bi < BB/NCH; ++bi) {
    const int ct = cnt_sh[bi];
    if (ct == 0) continue;
    const size_t kb = (size_t)(b_lo + bi)*TT;
    float mv = M[kb*N_HID + r];
    unsigned long long word = hsbits[kb*8 + hw];
    for (int t = 0; t < ct; ++t) {
      float mv_n = 0.f; unsigned long long word_n = 0ULL;
      if (t + 1 < ct) {
        mv_n = M[(kb + t + 1)*N_HID + r];
        word_n = hsbits[(kb + t + 1)*8 + hw];
      }
      #pragma unroll
      for (int ii = 0; ii < 16; ++ii)
        if ((word >> (sh + ii)) & 1ULL) acc[ii] += mv;
      mv = mv_n; word = word_n;
    }
  }
  #pragma unroll
  for (int ii = 0; ii < 16; ++ii)
    grp[(size_t)ch*(N_HID*N_HID) + (size_t)r*N_HID + h0 + ii] = acc[ii];
}

// ---------------- phase D: deterministic partial reductions ----------------
__global__ void k_gfred(const float* __restrict__ gfp, float* __restrict__ gf) {
  const int g = blockIdx.x*256 + threadIdx.x;
  if (g < N_HID*N_IN) {
    float s = 0.f;
    #pragma unroll
    for (int c = 0; c < NCH; ++c) s += gfp[(size_t)c*(N_HID*N_IN) + g];
    gf[g] = 0.1f*s;
  }
}
__global__ void k_grred(const float* __restrict__ grp, float* __restrict__ gr) {
  const int g = blockIdx.x*256 + threadIdx.x;
  if (g < N_HID*N_HID) {
    float s = 0.f;
    #pragma unroll
    for (int c = 0; c < NCH; ++c) s += grp[(size_t)c*(N_HID*N_HID) + g];
    gr[g] = 0.1f*s;
  }
}

extern "C" void kernel_launch(void* const* d_in, const int* in_sizes, int n_in,
                              void* d_out, int out_size, void* d_ws, size_t ws_size,
                              hipStream_t stream) {
  const float* x     = (const float*)d_in[0];
  const float* label = (const float*)d_in[1];
  const float* W1    = (const float*)d_in[2];
  const float* Wr    = (const float*)d_in[3];
  const float* Wo    = (const float*)d_in[4];

  float* out  = (float*)d_out;
  float* outs = out;                                    // [256][100][20]
  float* gf   = out + 512000;                           // [512][700]
  float* gr   = out + 512000 + 358400;                  // [512][512]
  float* go   = out + 512000 + 358400 + 262144;         // [20][512]

  char* ws = (char*)d_ws;
  size_t off = 0;
  auto alloc = [&](size_t bytes) -> char* {
    char* p = ws + off;
    off += (bytes + 255) & ~(size_t)255;
    return p;
  };
  float* INL = (float*)alloc((size_t)NK*N_HID*sizeof(float));                    // 52.43 MB
  unsigned long long* hsb = (unsigned long long*)alloc((size_t)NK*8*sizeof(unsigned long long)); // 1.64 MB
  int* tmax = (int*)alloc((size_t)BB*sizeof(int));
  char* uni = alloc((size_t)20971520);                                           // 20 MB union region

  // early residents of uni (dead after k_go)
  unsigned short* WH = (unsigned short*)(uni);                                   // 0.72 MB
  unsigned short* WL = (unsigned short*)(uni + 720896);                          // 0.72 MB
  float* WRT  = (float*)(uni + 2*720896);                                        // 1.05 MB
  float* Srow = (float*)(uni + 2*720896 + 1048576);
  float* SOs  = (float*)(uni + 2*720896 + 1048576 + 2048);
  float* pgo  = (float*)(uni + 2*720896 + 1048576 + 4096);                       // 10.49 MB
  // late residents of uni (written only after k_go has consumed pgo)
  float* gfp  = (float*)(uni);                                                   // 11.47 MB
  float* grp  = (float*)(uni + (size_t)NCH*N_HID*N_IN*sizeof(float));            // 8.39 MB

  k_wsplit<<<(N_HID*88 + 255)/256, 256, 0, stream>>>(W1, WH, WL);
  k_prep_t2<<<(N_HID*N_HID + 255)/256, 256, 0, stream>>>(Wr, WRT);
  k_prep_sums<<<(N_HID + N_OUT + 255)/256, 256, 0, stream>>>(Wr, Wo, Srow, SOs, tmax);
  dim3 gg(NK/128, N_HID/128);
  k_gemm<<<gg, 256, 0, stream>>>(x, WH, WL, INL);
  k_scan<<<BB, 256, 0, stream>>>(INL, label, Wo, WRT, Srow, SOs, hsb, outs, pgo);
  k_mfilter<<<(BB*N_HID)/256, 256, 0, stream>>>(INL, tmax);
  k_go<<<(N_OUT*N_HID)/64, 256, 0, stream>>>(pgo, go);
  dim3 ggf(8, 11, NCH); k_gf<<<ggf, 256, 0, stream>>>(INL, x, tmax, gfp);
  dim3 ggr(8, 8, NCH);  k_gr<<<ggr, 256, 0, stream>>>(INL, hsb, tmax, grp);
  k_gfred<<<(N_HID*N_IN + 255)/256, 256, 0, stream>>>(gfp, gf);
  k_grred<<<(N_HID*N_HID + 255)/256, 256, 0, stream>>>(grp, gr);
}